// Round 1
// baseline (634.654 us; speedup 1.0000x reference)
//
#include <hip/hip_runtime.h>
#include <math.h>

// Problem constants
#define BB 512
#define NN 10020
#define LL 20
#define SS 10
#define HH 1001   // (NN-LL)/SS + 1
#define HL (HH*LL)
#define INV_SQRT6 0.40824829046386296f
#define TPB 256
#define NT 4      // ceil(HH / TPB)

// Output layout (flat float offsets, in return order)
#define SZ_REC  (BB*NN*3)
#define SZ_BH3  (BB*HH*3)
#define SZ_ST   (BB*LL*HH*3)
#define SZ_ROT  (BB*HH*LL*3)
#define SZ_NH   (NN*HH)
#define O_REC   0
#define O_P     (O_REC + SZ_REC)
#define O_P1    (O_P   + SZ_BH3)
#define O_P2    (O_P1  + SZ_BH3)
#define O_ST    (O_P2  + SZ_BH3)
#define O_ROT   (O_ST  + SZ_ST)
#define O_NW    (O_ROT + SZ_ROT)
#define O_CT    (O_NW  + SZ_NH)

// --- K0: cos/sin + nw_g gather table (one thread per (h,l)) --------------
__global__ void k_tab(const float* __restrict__ ang, const float* __restrict__ W_enc,
                      float2* __restrict__ cs, float* __restrict__ gt) {
    int t = blockIdx.x * blockDim.x + threadIdx.x;
    if (t >= HL) return;
    float a = ang[t];
    cs[t] = make_float2(cosf(a), sinf(a));
    int h = t / LL, l = t - LL * (t / LL);
    int n = SS * h + l;
    // band of row n: [ended, hhi]; ct==1 throughout (proved: valid mask == ct mask)
    int ended = (n >= LL) ? (n - SS) / SS : 0;           // ceil((n-19)/10)
    int hhi = n / SS; if (hhi > HH - 1) hhi = HH - 1;
    float denom = 0.f;
    for (int hp = ended; hp <= hhi; ++hp)
        denom += W_enc[(size_t)((n - SS * hp) * HH + hp) * 3];
    gt[t] = W_enc[(size_t)(l * HH + h) * 3] / denom;
}

// --- K1: band fill of nw / ct (arrays pre-memset to 0); one thread per i -
__global__ void k_band(const float* __restrict__ W_enc,
                       float* __restrict__ nw, float* __restrict__ ct) {
    int i = blockIdx.x * blockDim.x + threadIdx.x;
    if (i >= NN) return;
    int ended = (i >= LL) ? (i - SS) / SS : 0;
    int hhi = i / SS; if (hhi > HH - 1) hhi = HH - 1;
    float denom = 0.f;
    for (int hp = ended; hp <= hhi; ++hp)
        denom += W_enc[(size_t)((i - SS * hp) * HH + hp) * 3];
    size_t row = (size_t)i * HH;
    for (int h = ended; h <= hhi; ++h) {
        ct[row + h] = 1.0f;
        nw[row + h] = W_enc[(size_t)((i - SS * h) * HH + h) * 3] / denom;
    }
}

// --- K2: main per-(b, h-tile) block kernel -------------------------------
// LDS: single 30.8 KB buffer, used as xs (x window) first, then reused as rb
// (recon accumulator) after all xs reads are done. With __launch_bounds__
// capping VGPR at 128, this gives 4 blocks/CU (16 waves/CU) vs 2 before.
__global__ void __launch_bounds__(TPB, 4) k_main(
    const float*  __restrict__ x,       const float* __restrict__ W_enc,
    const float*  __restrict__ W_dec,   const float* __restrict__ ang,
    const float2* __restrict__ cs_tab,  const float* __restrict__ g_tab,
    const float*  __restrict__ scaling, const float* __restrict__ nw,
    float* __restrict__ recon, float* __restrict__ Pout,
    float* __restrict__ p1out, float* __restrict__ p2out,
    float* __restrict__ stout, float* __restrict__ rotout) {

    __shared__ float xs[(SS*TPB + SS) * 3];   // 7710 floats = 30.84 KB
    float* rb = xs;                            // alias: rb reuses xs storage

    int tile = blockIdx.x & (NT - 1);
    int b    = blockIdx.x >> 2;
    int h0   = tile * TPB;
    int cnt  = HH - h0; if (cnt > TPB) cnt = TPB;
    int t    = threadIdx.x;
    int a0   = SS * h0;
    int nf   = (SS * cnt + SS) * 3;

    // stage x window (coalesced, float4: offset b*30060 + tile*7680 is 0 mod 4)
    const float* xsrc = x + ((size_t)b * NN + a0) * 3;
    {
        const float4* xs4 = (const float4*)xsrc;
        float4* xl4 = (float4*)xs;
        int nf4 = nf >> 2;
        for (int j = t; j < nf4; j += TPB) xl4[j] = xs4[j];
        for (int j = (nf4 << 2) + t; j < nf; j += TPB) xs[j] = xsrc[j];
    }
    __syncthreads();

    // st writes: fully coalesced contiguous dword stores per i
    for (int i = 0; i < LL; ++i) {
        float* dst = stout + (((size_t)b * LL + i) * HH + h0) * 3;
        for (int j = t; j < cnt * 3; j += TPB) {
            int hh = j / 3, k = j - 3 * hh;
            dst[j] = xs[(SS * hh + i) * 3 + k];
        }
    }

    int h = h0 + t;
    float Px=0,Py=0,Pz=0, p1x=0,p1y=0,p1z=0, p2x=0,p2y=0,p2z=0;
    float cx=0, cy=0, cz=0;
    const float* wd0 = nullptr; const float* wd1 = nullptr; const float* wd2 = nullptr;

    if (t < cnt) {
        float e00=0,e01=0,e02=0, e10=0,e11=0,e12=0, e20=0,e21=0,e22=0;
        const float* xl = xs + (size_t)SS * t * 3;
#pragma unroll
        for (int i = 0; i < LL; ++i) {
            float v0 = xl[i*3+0], v1 = xl[i*3+1], v2 = xl[i*3+2];
            const float* we = W_enc + ((size_t)i * HH + h) * 3;
            float w0 = we[0], w1 = we[1], w2 = we[2];
            e00 = fmaf(v0, w0, e00); e01 = fmaf(v1, w0, e01); e02 = fmaf(v2, w0, e02);
            e10 = fmaf(v0, w1, e10); e11 = fmaf(v1, w1, e11); e12 = fmaf(v2, w1, e12);
            e20 = fmaf(v0, w2, e20); e21 = fmaf(v1, w2, e21); e22 = fmaf(v2, w2, e22);
        }
        Px = e00; Py = e01; Pz = e02;
        float d1x = e10-Px, d1y = e11-Py, d1z = e12-Pz;
        float d2x = e20-Px, d2y = e21-Py, d2z = e22-Pz;
        float n1 = sqrtf(d1x*d1x + d1y*d1y + d1z*d1z); if (n1 == 0.f) n1 = 1.f;
        float n2 = sqrtf(d2x*d2x + d2y*d2y + d2z*d2z); if (n2 == 0.f) n2 = 1.f;
        p1x = d1x/n1; p1y = d1y/n1; p1z = d1z/n1;
        p2x = d2x/n2; p2y = d2y/n2; p2z = d2z/n2;
        cx = (p1y*p2z - p1z*p2y) * INV_SQRT6;
        cy = (p1z*p2x - p1x*p2z) * INV_SQRT6;
        cz = (p1x*p2y - p1y*p2x) * INV_SQRT6;

        size_t bh = (size_t)b * HH + h;
        Pout [bh*3+0]=Px;  Pout [bh*3+1]=Py;  Pout [bh*3+2]=Pz;
        p1out[bh*3+0]=p1x; p1out[bh*3+1]=p1y; p1out[bh*3+2]=p1z;
        p2out[bh*3+0]=p2x; p2out[bh*3+1]=p2y; p2out[bh*3+2]=p2z;

        wd0 = W_dec + (size_t)h * LL;
        wd1 = wd0 + (size_t)HH * LL;
        wd2 = wd1 + (size_t)HH * LL;

        // rot_axes: compute in 4-l chunks, write as float4 (no ra[60] array)
        float4* ro4 = (float4*)(rotout + bh * (size_t)(LL*3));
#pragma unroll
        for (int lq = 0; lq < LL/4; ++lq) {
            float v[12];
#pragma unroll
            for (int u = 0; u < 4; ++u) {
                int l = 4*lq + u;
                float w0 = wd0[l], w1 = wd1[l], w2 = wd2[l];
                v[3*u+0] = fmaf(p1x, w0, fmaf(p2x, w1, cx*w2));
                v[3*u+1] = fmaf(p1y, w0, fmaf(p2y, w1, cy*w2));
                v[3*u+2] = fmaf(p1z, w0, fmaf(p2z, w1, cz*w2));
            }
            ro4[3*lq+0] = make_float4(v[0], v[1], v[2],  v[3]);
            ro4[3*lq+1] = make_float4(v[4], v[5], v[6],  v[7]);
            ro4[3*lq+2] = make_float4(v[8], v[9], v[10], v[11]);
        }
    }
    __syncthreads();   // all xs reads complete; safe to reuse LDS as rb

    // recon contribution for (h, l) -> c3[3]; rot axis recomputed from regs
    auto contrib = [&](int l, float* c3) {
        float w0 = wd0[l], w1 = wd1[l], w2 = wd2[l];
        float r0 = fmaf(p1x, w0, fmaf(p2x, w1, cx*w2));
        float r1 = fmaf(p1y, w0, fmaf(p2y, w1, cy*w2));
        float r2 = fmaf(p1z, w0, fmaf(p2z, w1, cz*w2));
        float ca, sa, g;
        if (cs_tab) {
            float2 c2 = cs_tab[h*LL + l]; ca = c2.x; sa = c2.y;
            g = g_tab[h*LL + l];
        } else {
            float a = ang[h*LL + l]; ca = cosf(a); sa = sinf(a);
            g = nw[(size_t)(SS*h + l) * HH + h];
        }
        float qx = sa*r0, qy = sa*r1, qz = sa*r2;
        float tt = ca*ca - (qx*qx + qy*qy + qz*qz);
        float rv = qx*p1x + qy*p1y + qz*p1z;
        float axv = qy*p1z - qz*p1y;
        float ayv = qz*p1x - qx*p1z;
        float azv = qx*p1y - qy*p1x;
        float sc = scaling[SS*h + l];
        c3[0] = (sc * (tt*p1x + 2.f*(rv*qx + ca*axv)) + Px) * g;
        c3[1] = (sc * (tt*p1y + 2.f*(rv*qy + ca*ayv)) + Py) * g;
        c3[2] = (sc * (tt*p1z + 2.f*(rv*qz + ca*azv)) + Pz) * g;
    };

    // phase A: low halves (and high half for the last thread) -> LDS write
    if (t < cnt) {
        for (int l = 0; l < SS; ++l) {
            float c3[3]; contrib(l, c3);
            rb[30*t + 3*l + 0] = c3[0];
            rb[30*t + 3*l + 1] = c3[1];
            rb[30*t + 3*l + 2] = c3[2];
        }
        if (t == cnt - 1) {
            for (int l = SS; l < LL; ++l) {
                float c3[3]; contrib(l, c3);
                rb[30*t + 3*l + 0] = c3[0];
                rb[30*t + 3*l + 1] = c3[1];
                rb[30*t + 3*l + 2] = c3[2];
            }
        }
    }
    __syncthreads();
    // phase B: high halves accumulate into neighbor's slots
    if (t < cnt - 1) {
        for (int l = SS; l < LL; ++l) {
            float c3[3]; contrib(l, c3);
            rb[30*t + 3*l + 0] += c3[0];
            rb[30*t + 3*l + 1] += c3[1];
            rb[30*t + 3*l + 2] += c3[2];
        }
    }
    __syncthreads();

    // interior atoms: plain coalesced store; 2x10 boundary atoms: atomicAdd
    float* rdst = recon + ((size_t)b * NN + a0) * 3;
    int interiorEnd = 30 * cnt;
    for (int j = 30 + t; j < interiorEnd; j += TPB) rdst[j] = rb[j];
    if (t < 30) atomicAdd(rdst + t, rb[t]);
    if (t >= 64 && t < 94) {
        int j = interiorEnd + (t - 64);
        atomicAdd(rdst + j, rb[j]);
    }
}

extern "C" void kernel_launch(void* const* d_in, const int* in_sizes, int n_in,
                              void* d_out, int out_size, void* d_ws, size_t ws_size,
                              hipStream_t stream) {
    const float* x       = (const float*)d_in[0];
    const float* W_enc   = (const float*)d_in[1];
    const float* W_dec   = (const float*)d_in[2];
    const float* ang     = (const float*)d_in[3];
    const float* scaling = (const float*)d_in[4];
    float* out = (float*)d_out;

    float2* cs = nullptr; float* gt = nullptr;
    size_t need = (size_t)HL * (sizeof(float2) + sizeof(float));
    if (ws_size >= need) {
        cs = (float2*)d_ws;
        gt = (float*)(cs + HL);
    }

    // zero recon (atomic/accumulate base) and the nw/ct region (sparse band)
    hipMemsetAsync(out + O_REC, 0, (size_t)SZ_REC * sizeof(float), stream);
    hipMemsetAsync(out + O_NW, 0, (size_t)(2 * SZ_NH) * sizeof(float), stream);

    if (cs) k_tab<<<(HL + 255)/256, 256, 0, stream>>>(ang, W_enc, cs, gt);
    k_band<<<(NN + 255)/256, 256, 0, stream>>>(W_enc, out + O_NW, out + O_CT);

    k_main<<<BB * NT, TPB, 0, stream>>>(
        x, W_enc, W_dec, ang, cs, gt, scaling, out + O_NW,
        out + O_REC, out + O_P, out + O_P1, out + O_P2, out + O_ST, out + O_ROT);
}

// Round 2
// 523.562 us; speedup vs baseline: 1.2122x; 1.2122x over previous
//
#include <hip/hip_runtime.h>
#include <math.h>

// Problem constants
#define BB 512
#define NN 10020
#define LL 20
#define SS 10
#define HH 1001   // (NN-LL)/SS + 1
#define HL (HH*LL)
#define INV_SQRT6 0.40824829046386296f
#define TPB 256
#define NT 4      // ceil(HH / TPB)

// Output layout (flat float offsets, in return order)
#define SZ_REC  (BB*NN*3)
#define SZ_BH3  (BB*HH*3)
#define SZ_ST   (BB*LL*HH*3)
#define SZ_ROT  (BB*HH*LL*3)
#define SZ_NH   (NN*HH)
#define O_REC   0
#define O_P     (O_REC + SZ_REC)
#define O_P1    (O_P   + SZ_BH3)
#define O_P2    (O_P1  + SZ_BH3)
#define O_ST    (O_P2  + SZ_BH3)
#define O_ROT   (O_ST  + SZ_ST)
#define O_NW    (O_ROT + SZ_ROT)
#define O_CT    (O_NW  + SZ_NH)

// --- K0: build transposed fused tables in workspace ----------------------
//   tab4[l*HH + h] = {cos(a), sin(a), scaling*g, g}   (g = nw gather value)
//   wd4 [l*HH + h] = {W_dec[0][h][l], W_dec[1][h][l], W_dec[2][h][l], 0}
// h is the fast index -> k_main reads are lane-coalesced float4 loads.
__global__ void k_tab(const float* __restrict__ ang, const float* __restrict__ W_enc,
                      const float* __restrict__ W_dec, const float* __restrict__ scaling,
                      float4* __restrict__ tab4, float4* __restrict__ wd4) {
    int t = blockIdx.x * blockDim.x + threadIdx.x;
    if (t >= HL) return;
    int l = t / HH, h = t - HH * l;          // h fast for coalesced writes
    int n = SS * h + l;
    // band of row n: [ended, hhi]; ct==1 throughout (valid mask == ct mask)
    int ended = (n >= LL) ? (n - SS) / SS : 0;
    int hhi = n / SS; if (hhi > HH - 1) hhi = HH - 1;
    float denom = 0.f;
    for (int hp = ended; hp <= hhi; ++hp)
        denom += W_enc[(size_t)((n - SS * hp) * HH + hp) * 3];
    float g = W_enc[(size_t)(l * HH + h) * 3] / denom;
    float a = ang[h * LL + l];
    float sc = scaling[n];
    tab4[t] = make_float4(cosf(a), sinf(a), sc * g, g);
    wd4[t]  = make_float4(W_dec[(size_t)h * LL + l],
                          W_dec[(size_t)(HH * LL) + (size_t)h * LL + l],
                          W_dec[(size_t)(2 * HH * LL) + (size_t)h * LL + l], 0.f);
}

// --- K1: band fill of nw / ct (arrays pre-memset to 0); one thread per i -
__global__ void k_band(const float* __restrict__ W_enc,
                       float* __restrict__ nw, float* __restrict__ ct) {
    int i = blockIdx.x * blockDim.x + threadIdx.x;
    if (i >= NN) return;
    int ended = (i >= LL) ? (i - SS) / SS : 0;
    int hhi = i / SS; if (hhi > HH - 1) hhi = HH - 1;
    float denom = 0.f;
    for (int hp = ended; hp <= hhi; ++hp)
        denom += W_enc[(size_t)((i - SS * hp) * HH + hp) * 3];
    size_t row = (size_t)i * HH;
    for (int h = ended; h <= hhi; ++h) {
        ct[row + h] = 1.0f;
        nw[row + h] = W_enc[(size_t)((i - SS * h) * HH + h) * 3] / denom;
    }
}

// --- K2: main per-(b, h-tile) block kernel -------------------------------
// Single 30.8 KB LDS buffer: used as xs (x window) first, then reused as rb
// (recon accumulator) once all xs reads are done. No forced VGPR cap (round-1
// lesson: launch_bounds(…,4) caused spills). ra[60] kept in registers.
__global__ void __launch_bounds__(TPB) k_main(
    const float*  __restrict__ x,       const float* __restrict__ W_enc,
    const float*  __restrict__ W_dec,   const float* __restrict__ ang,
    const float4* __restrict__ tab4,    const float4* __restrict__ wd4,
    const float*  __restrict__ scaling, const float* __restrict__ nw,
    float* __restrict__ recon, float* __restrict__ Pout,
    float* __restrict__ p1out, float* __restrict__ p2out,
    float* __restrict__ stout, float* __restrict__ rotout) {

    __shared__ float xs[(SS*TPB + SS) * 3];   // 7710 floats = 30.84 KB
    float* rb = xs;                            // alias: rb reuses xs storage

    int tile = blockIdx.x & (NT - 1);
    int b    = blockIdx.x >> 2;
    int h0   = tile * TPB;
    int cnt  = HH - h0; if (cnt > TPB) cnt = TPB;
    int t    = threadIdx.x;
    int a0   = SS * h0;
    int nf   = (SS * cnt + SS) * 3;

    // stage x window (coalesced float4; offset b*30060 + tile*7680 is 0 mod 4)
    const float* xsrc = x + ((size_t)b * NN + a0) * 3;
    {
        const float4* xs4 = (const float4*)xsrc;
        float4* xl4 = (float4*)xs;
        int nf4 = nf >> 2;
        for (int j = t; j < nf4; j += TPB) xl4[j] = xs4[j];
        for (int j = (nf4 << 2) + t; j < nf; j += TPB) xs[j] = xsrc[j];
    }
    __syncthreads();

    // st writes: float4-vectorized with alignment peel (dst offset mod 4 == (3i)&3)
    {
        int M = cnt * 3;
        for (int i = 0; i < LL; ++i) {
            float* dst = stout + (((size_t)b * LL + i) * HH + h0) * 3;
            int pre = i & 3;                   // scalars before 16B alignment
            if (t < pre) {
                int hh = t / 3, k = t - 3 * hh;
                dst[t] = xs[(SS * hh + i) * 3 + k];
            }
            int nv4 = (M - pre) >> 2;
            float4* d4 = (float4*)(dst + pre);
            for (int q = t; q < nv4; q += TPB) {
                int j = pre + 4 * q;
                int h0i = j / 3, k0 = j - 3 * h0i;
                float4 v;
                v.x = xs[(SS * h0i + i) * 3 + k0];
                int j1 = j + 1; int h1i = j1 / 3, k1 = j1 - 3 * h1i;
                v.y = xs[(SS * h1i + i) * 3 + k1];
                int j2 = j + 2; int h2i = j2 / 3, k2 = j2 - 3 * h2i;
                v.z = xs[(SS * h2i + i) * 3 + k2];
                int j3 = j + 3; int h3i = j3 / 3, k3 = j3 - 3 * h3i;
                v.w = xs[(SS * h3i + i) * 3 + k3];
                d4[q] = v;
            }
            for (int j = pre + (nv4 << 2) + t; j < M; j += TPB) {
                int hh = j / 3, k = j - 3 * hh;
                dst[j] = xs[(SS * hh + i) * 3 + k];
            }
        }
    }

    int h = h0 + t;
    float Px=0,Py=0,Pz=0, p1x=0,p1y=0,p1z=0, p2x=0,p2y=0,p2z=0;
    float ra[3 * LL];

    if (t < cnt) {
        float e00=0,e01=0,e02=0, e10=0,e11=0,e12=0, e20=0,e21=0,e22=0;
        const float* xl = xs + (size_t)SS * t * 3;
#pragma unroll
        for (int i = 0; i < LL; ++i) {
            float v0 = xl[i*3+0], v1 = xl[i*3+1], v2 = xl[i*3+2];
            const float* we = W_enc + ((size_t)i * HH + h) * 3;
            float w0 = we[0], w1 = we[1], w2 = we[2];
            e00 = fmaf(v0, w0, e00); e01 = fmaf(v1, w0, e01); e02 = fmaf(v2, w0, e02);
            e10 = fmaf(v0, w1, e10); e11 = fmaf(v1, w1, e11); e12 = fmaf(v2, w1, e12);
            e20 = fmaf(v0, w2, e20); e21 = fmaf(v1, w2, e21); e22 = fmaf(v2, w2, e22);
        }
        Px = e00; Py = e01; Pz = e02;
        float d1x = e10-Px, d1y = e11-Py, d1z = e12-Pz;
        float d2x = e20-Px, d2y = e21-Py, d2z = e22-Pz;
        float n1 = sqrtf(d1x*d1x + d1y*d1y + d1z*d1z); if (n1 == 0.f) n1 = 1.f;
        float n2 = sqrtf(d2x*d2x + d2y*d2y + d2z*d2z); if (n2 == 0.f) n2 = 1.f;
        p1x = d1x/n1; p1y = d1y/n1; p1z = d1z/n1;
        p2x = d2x/n2; p2y = d2y/n2; p2z = d2z/n2;
        float cx = (p1y*p2z - p1z*p2y) * INV_SQRT6;
        float cy = (p1z*p2x - p1x*p2z) * INV_SQRT6;
        float cz = (p1x*p2y - p1y*p2x) * INV_SQRT6;

        size_t bh = (size_t)b * HH + h;
        Pout [bh*3+0]=Px;  Pout [bh*3+1]=Py;  Pout [bh*3+2]=Pz;
        p1out[bh*3+0]=p1x; p1out[bh*3+1]=p1y; p1out[bh*3+2]=p1z;
        p2out[bh*3+0]=p2x; p2out[bh*3+1]=p2y; p2out[bh*3+2]=p2z;

        if (wd4) {
#pragma unroll
            for (int l = 0; l < LL; ++l) {
                float4 w = wd4[l * HH + h];    // coalesced 16B per lane
                ra[l*3+0] = fmaf(p1x, w.x, fmaf(p2x, w.y, cx*w.z));
                ra[l*3+1] = fmaf(p1y, w.x, fmaf(p2y, w.y, cy*w.z));
                ra[l*3+2] = fmaf(p1z, w.x, fmaf(p2z, w.y, cz*w.z));
            }
        } else {
            const float* wd0 = W_dec + (size_t)h * LL;
            const float* wd1 = wd0 + (size_t)HH * LL;
            const float* wd2 = wd1 + (size_t)HH * LL;
#pragma unroll
            for (int l = 0; l < LL; ++l) {
                float w0 = wd0[l], w1 = wd1[l], w2 = wd2[l];
                ra[l*3+0] = fmaf(p1x, w0, fmaf(p2x, w1, cx*w2));
                ra[l*3+1] = fmaf(p1y, w0, fmaf(p2y, w1, cy*w2));
                ra[l*3+2] = fmaf(p1z, w0, fmaf(p2z, w1, cz*w2));
            }
        }
        float4* ro4 = (float4*)(rotout + bh * (size_t)(LL*3));
#pragma unroll
        for (int q = 0; q < (3*LL)/4; ++q)
            ro4[q] = make_float4(ra[4*q+0], ra[4*q+1], ra[4*q+2], ra[4*q+3]);
    }
    __syncthreads();   // all xs reads complete; safe to reuse LDS as rb

    // recon contribution for (h, l) -> c3[3]; tables are one coalesced float4
    auto contrib = [&](int l, float* c3) {
        float r0 = ra[l*3+0], r1 = ra[l*3+1], r2 = ra[l*3+2];
        float ca, sa, sg, g;
        if (tab4) {
            float4 tv = tab4[l * HH + h];      // coalesced 16B per lane
            ca = tv.x; sa = tv.y; sg = tv.z; g = tv.w;
        } else {
            float a = ang[h*LL + l]; ca = cosf(a); sa = sinf(a);
            g = nw[(size_t)(SS*h + l) * HH + h];
            sg = scaling[SS*h + l] * g;
        }
        float qx = sa*r0, qy = sa*r1, qz = sa*r2;
        float tt = ca*ca - (qx*qx + qy*qy + qz*qz);
        float rv = qx*p1x + qy*p1y + qz*p1z;
        float axv = qy*p1z - qz*p1y;
        float ayv = qz*p1x - qx*p1z;
        float azv = qx*p1y - qy*p1x;
        c3[0] = fmaf(sg, fmaf(tt, p1x, 2.f*fmaf(rv, qx, ca*axv)), g*Px);
        c3[1] = fmaf(sg, fmaf(tt, p1y, 2.f*fmaf(rv, qy, ca*ayv)), g*Py);
        c3[2] = fmaf(sg, fmaf(tt, p1z, 2.f*fmaf(rv, qz, ca*azv)), g*Pz);
    };

    // phase A: low halves (and high half for the last thread) -> LDS write
    if (t < cnt) {
        for (int l = 0; l < SS; ++l) {
            float c3[3]; contrib(l, c3);
            rb[30*t + 3*l + 0] = c3[0];
            rb[30*t + 3*l + 1] = c3[1];
            rb[30*t + 3*l + 2] = c3[2];
        }
        if (t == cnt - 1) {
            for (int l = SS; l < LL; ++l) {
                float c3[3]; contrib(l, c3);
                rb[30*t + 3*l + 0] = c3[0];
                rb[30*t + 3*l + 1] = c3[1];
                rb[30*t + 3*l + 2] = c3[2];
            }
        }
    }
    __syncthreads();
    // phase B: high halves accumulate into neighbor's slots
    if (t < cnt - 1) {
        for (int l = SS; l < LL; ++l) {
            float c3[3]; contrib(l, c3);
            rb[30*t + 3*l + 0] += c3[0];
            rb[30*t + 3*l + 1] += c3[1];
            rb[30*t + 3*l + 2] += c3[2];
        }
    }
    __syncthreads();

    // interior atoms: float4 stores (base is 16B-aligned); boundary: atomicAdd
    float* rdst = recon + ((size_t)b * NN + a0) * 3;
    int interiorEnd = 30 * cnt;
    {
        int ie4 = interiorEnd >> 2;
        float4* r4 = (float4*)rdst;
        for (int q = 8 + t; q < ie4; q += TPB)   // j = 32 .. 4*ie4-1
            r4[q] = make_float4(rb[4*q+0], rb[4*q+1], rb[4*q+2], rb[4*q+3]);
        if (t < 2) rdst[30 + t] = rb[30 + t];    // j = 30, 31
        for (int j = (ie4 << 2) + t; j < interiorEnd; j += TPB) rdst[j] = rb[j];
    }
    if (t < 30) atomicAdd(rdst + t, rb[t]);
    if (t >= 64 && t < 94) {
        int j = interiorEnd + (t - 64);
        atomicAdd(rdst + j, rb[j]);
    }
}

extern "C" void kernel_launch(void* const* d_in, const int* in_sizes, int n_in,
                              void* d_out, int out_size, void* d_ws, size_t ws_size,
                              hipStream_t stream) {
    const float* x       = (const float*)d_in[0];
    const float* W_enc   = (const float*)d_in[1];
    const float* W_dec   = (const float*)d_in[2];
    const float* ang     = (const float*)d_in[3];
    const float* scaling = (const float*)d_in[4];
    float* out = (float*)d_out;

    float4* tab4 = nullptr; float4* wd4 = nullptr;
    size_t need = (size_t)HL * sizeof(float4) * 2;   // 640 KB
    if (ws_size >= need) {
        tab4 = (float4*)d_ws;
        wd4  = tab4 + HL;
    }

    // zero recon (atomic/accumulate base) and the nw/ct region (sparse band)
    hipMemsetAsync(out + O_REC, 0, (size_t)SZ_REC * sizeof(float), stream);
    hipMemsetAsync(out + O_NW, 0, (size_t)(2 * SZ_NH) * sizeof(float), stream);

    if (tab4) k_tab<<<(HL + 255)/256, 256, 0, stream>>>(ang, W_enc, W_dec, scaling, tab4, wd4);
    k_band<<<(NN + 255)/256, 256, 0, stream>>>(W_enc, out + O_NW, out + O_CT);

    k_main<<<BB * NT, TPB, 0, stream>>>(
        x, W_enc, W_dec, ang, tab4, wd4, scaling, out + O_NW,
        out + O_REC, out + O_P, out + O_P1, out + O_P2, out + O_ST, out + O_ROT);
}

// Round 4
// 504.623 us; speedup vs baseline: 1.2577x; 1.0375x over previous
//
#include <hip/hip_runtime.h>
#include <math.h>

// Problem constants
#define BB 512
#define NN 10020
#define LL 20
#define SS 10
#define HH 1001   // (NN-LL)/SS + 1
#define HL (HH*LL)
#define INV_SQRT6 0.40824829046386296f
#define TPB 256
#define NT 4      // ceil(HH / TPB)

// Output layout (flat float offsets, in return order)
#define SZ_REC  (BB*NN*3)
#define SZ_BH3  (BB*HH*3)
#define SZ_ST   (BB*LL*HH*3)
#define SZ_ROT  (BB*HH*LL*3)
#define SZ_NH   (NN*HH)
#define O_REC   0
#define O_P     (O_REC + SZ_REC)
#define O_P1    (O_P   + SZ_BH3)
#define O_P2    (O_P1  + SZ_BH3)
#define O_ST    (O_P2  + SZ_BH3)
#define O_ROT   (O_ST  + SZ_ST)
#define O_NW    (O_ROT + SZ_ROT)
#define O_CT    (O_NW  + SZ_NH)

// --- K0: build transposed fused tables in workspace ----------------------
//   tab4[l*HH + h] = {cos(a), sin(a), scaling*g, g}   (g = nw gather value)
//   wd4 [l*HH + h] = {W_dec[0][h][l], W_dec[1][h][l], W_dec[2][h][l], 0}
// h is the fast index -> k_main reads are lane-coalesced float4 loads.
__global__ void k_tab(const float* __restrict__ ang, const float* __restrict__ W_enc,
                      const float* __restrict__ W_dec, const float* __restrict__ scaling,
                      float4* __restrict__ tab4, float4* __restrict__ wd4) {
    int t = blockIdx.x * blockDim.x + threadIdx.x;
    if (t >= HL) return;
    int l = t / HH, h = t - HH * l;          // h fast for coalesced writes
    int n = SS * h + l;
    // band of row n: [ended, hhi]; ct==1 throughout (valid mask == ct mask)
    int ended = (n >= LL) ? (n - SS) / SS : 0;
    int hhi = n / SS; if (hhi > HH - 1) hhi = HH - 1;
    float denom = 0.f;
    for (int hp = ended; hp <= hhi; ++hp)
        denom += W_enc[(size_t)((n - SS * hp) * HH + hp) * 3];
    float g = W_enc[(size_t)(l * HH + h) * 3] / denom;
    float a = ang[h * LL + l];
    float sc = scaling[n];
    tab4[t] = make_float4(cosf(a), sinf(a), sc * g, g);
    wd4[t]  = make_float4(W_dec[(size_t)h * LL + l],
                          W_dec[(size_t)(HH * LL) + (size_t)h * LL + l],
                          W_dec[(size_t)(2 * HH * LL) + (size_t)h * LL + l], 0.f);
}

// --- K1: band fill of nw / ct (arrays pre-memset to 0); one thread per i -
__global__ void k_band(const float* __restrict__ W_enc,
                       float* __restrict__ nw, float* __restrict__ ct) {
    int i = blockIdx.x * blockDim.x + threadIdx.x;
    if (i >= NN) return;
    int ended = (i >= LL) ? (i - SS) / SS : 0;
    int hhi = i / SS; if (hhi > HH - 1) hhi = HH - 1;
    float denom = 0.f;
    for (int hp = ended; hp <= hhi; ++hp)
        denom += W_enc[(size_t)((i - SS * hp) * HH + hp) * 3];
    size_t row = (size_t)i * HH;
    for (int h = ended; h <= hhi; ++h) {
        ct[row + h] = 1.0f;
        nw[row + h] = W_enc[(size_t)((i - SS * h) * HH + h) * 3] / denom;
    }
}

// --- K2: main per-(b, h-tile) block kernel -------------------------------
// Single 30.8 KB LDS buffer with three lives:
//   1. xs: staged x window (st writes + emb reads)
//   2. transpose buffer for coalesced rot_axes stores (two 128-row passes)
//   3. rb: recon accumulator
__global__ void __launch_bounds__(TPB) k_main(
    const float*  __restrict__ x,       const float* __restrict__ W_enc,
    const float*  __restrict__ W_dec,   const float* __restrict__ ang,
    const float4* __restrict__ tab4,    const float4* __restrict__ wd4,
    const float*  __restrict__ scaling, const float* __restrict__ nw,
    float* __restrict__ recon, float* __restrict__ Pout,
    float* __restrict__ p1out, float* __restrict__ p2out,
    float* __restrict__ stout, float* __restrict__ rotout) {

    __shared__ __align__(16) float xs[(SS*TPB + SS) * 3];   // 7710 floats = 30.84 KB
    float* rb = xs;                            // alias: rb reuses xs storage

    int tile = blockIdx.x & (NT - 1);
    int b    = blockIdx.x >> 2;
    int h0   = tile * TPB;
    int cnt  = HH - h0; if (cnt > TPB) cnt = TPB;
    int t    = threadIdx.x;
    int a0   = SS * h0;
    int nf   = (SS * cnt + SS) * 3;

    // stage x window (coalesced float4; offset b*30060 + tile*7680 is 0 mod 4)
    const float* xsrc = x + ((size_t)b * NN + a0) * 3;
    {
        const float4* xs4 = (const float4*)xsrc;
        float4* xl4 = (float4*)xs;
        int nf4 = nf >> 2;
        for (int j = t; j < nf4; j += TPB) xl4[j] = xs4[j];
        for (int j = (nf4 << 2) + t; j < nf; j += TPB) xs[j] = xsrc[j];
    }
    __syncthreads();

    // st writes: float4-vectorized with alignment peel (dst offset mod 4 == (3i)&3)
    {
        int M = cnt * 3;
        for (int i = 0; i < LL; ++i) {
            float* dst = stout + (((size_t)b * LL + i) * HH + h0) * 3;
            int pre = i & 3;                   // scalars before 16B alignment
            if (t < pre) {
                int hh = t / 3, k = t - 3 * hh;
                dst[t] = xs[(SS * hh + i) * 3 + k];
            }
            int nv4 = (M - pre) >> 2;
            float4* d4 = (float4*)(dst + pre);
            for (int q = t; q < nv4; q += TPB) {
                int j = pre + 4 * q;
                int h0i = j / 3, k0 = j - 3 * h0i;
                float4 v;
                v.x = xs[(SS * h0i + i) * 3 + k0];
                int j1 = j + 1; int h1i = j1 / 3, k1 = j1 - 3 * h1i;
                v.y = xs[(SS * h1i + i) * 3 + k1];
                int j2 = j + 2; int h2i = j2 / 3, k2 = j2 - 3 * h2i;
                v.z = xs[(SS * h2i + i) * 3 + k2];
                int j3 = j + 3; int h3i = j3 / 3, k3 = j3 - 3 * h3i;
                v.w = xs[(SS * h3i + i) * 3 + k3];
                d4[q] = v;
            }
            for (int j = pre + (nv4 << 2) + t; j < M; j += TPB) {
                int hh = j / 3, k = j - 3 * hh;
                dst[j] = xs[(SS * hh + i) * 3 + k];
            }
        }
    }

    int h = h0 + t;
    float Px=0,Py=0,Pz=0, p1x=0,p1y=0,p1z=0, p2x=0,p2y=0,p2z=0;
    float ra[3 * LL];

    if (t < cnt) {
        float e00=0,e01=0,e02=0, e10=0,e11=0,e12=0, e20=0,e21=0,e22=0;
        const float* xl = xs + (size_t)SS * t * 3;
#pragma unroll
        for (int i = 0; i < LL; ++i) {
            float v0 = xl[i*3+0], v1 = xl[i*3+1], v2 = xl[i*3+2];
            const float* we = W_enc + ((size_t)i * HH + h) * 3;
            float w0 = we[0], w1 = we[1], w2 = we[2];
            e00 = fmaf(v0, w0, e00); e01 = fmaf(v1, w0, e01); e02 = fmaf(v2, w0, e02);
            e10 = fmaf(v0, w1, e10); e11 = fmaf(v1, w1, e11); e12 = fmaf(v2, w1, e12);
            e20 = fmaf(v0, w2, e20); e21 = fmaf(v1, w2, e21); e22 = fmaf(v2, w2, e22);
        }
        Px = e00; Py = e01; Pz = e02;
        float d1x = e10-Px, d1y = e11-Py, d1z = e12-Pz;
        float d2x = e20-Px, d2y = e21-Py, d2z = e22-Pz;
        float n1 = sqrtf(d1x*d1x + d1y*d1y + d1z*d1z); if (n1 == 0.f) n1 = 1.f;
        float n2 = sqrtf(d2x*d2x + d2y*d2y + d2z*d2z); if (n2 == 0.f) n2 = 1.f;
        p1x = d1x/n1; p1y = d1y/n1; p1z = d1z/n1;
        p2x = d2x/n2; p2y = d2y/n2; p2z = d2z/n2;
        float cx = (p1y*p2z - p1z*p2y) * INV_SQRT6;
        float cy = (p1z*p2x - p1x*p2z) * INV_SQRT6;
        float cz = (p1x*p2y - p1y*p2x) * INV_SQRT6;

        size_t bh = (size_t)b * HH + h;
        Pout [bh*3+0]=Px;  Pout [bh*3+1]=Py;  Pout [bh*3+2]=Pz;
        p1out[bh*3+0]=p1x; p1out[bh*3+1]=p1y; p1out[bh*3+2]=p1z;
        p2out[bh*3+0]=p2x; p2out[bh*3+1]=p2y; p2out[bh*3+2]=p2z;

        if (wd4) {
#pragma unroll
            for (int l = 0; l < LL; ++l) {
                float4 w = wd4[l * HH + h];    // coalesced 16B per lane
                ra[l*3+0] = fmaf(p1x, w.x, fmaf(p2x, w.y, cx*w.z));
                ra[l*3+1] = fmaf(p1y, w.x, fmaf(p2y, w.y, cy*w.z));
                ra[l*3+2] = fmaf(p1z, w.x, fmaf(p2z, w.y, cz*w.z));
            }
        } else {
            const float* wd0 = W_dec + (size_t)h * LL;
            const float* wd1 = wd0 + (size_t)HH * LL;
            const float* wd2 = wd1 + (size_t)HH * LL;
#pragma unroll
            for (int l = 0; l < LL; ++l) {
                float w0 = wd0[l], w1 = wd1[l], w2 = wd2[l];
                ra[l*3+0] = fmaf(p1x, w0, fmaf(p2x, w1, cx*w2));
                ra[l*3+1] = fmaf(p1y, w0, fmaf(p2y, w1, cy*w2));
                ra[l*3+2] = fmaf(p1z, w0, fmaf(p2z, w1, cz*w2));
            }
        }
    }
    __syncthreads();   // all xs reads complete; LDS free for rot transpose

    // rot_axes store via LDS transpose: two 128-row passes, coalesced float4.
    // (Direct per-thread store had lane-stride 240 B -> 64 cache lines per
    //  wave-store; this form is 16 lines per wave-store.)
    for (int half = 0; half < 2; ++half) {
        int hb = half * 128;
        int rows = cnt - hb; if (rows > 128) rows = 128;
        if (rows <= 0) break;
        if (t >= hb && t < hb + rows) {
            float4* dst = (float4*)(rb + (size_t)(t - hb) * 60);
#pragma unroll
            for (int q = 0; q < 15; ++q)
                dst[q] = make_float4(ra[4*q+0], ra[4*q+1], ra[4*q+2], ra[4*q+3]);
        }
        __syncthreads();
        {
            float4* ro4 = (float4*)(rotout + ((size_t)b * HH + h0 + hb) * 60);
            const float4* rb4 = (const float4*)rb;
            int nq = rows * 15;
            for (int q = t; q < nq; q += TPB) ro4[q] = rb4[q];
        }
        __syncthreads();
    }

    // recon contribution for (h, l) -> c3[3]; tables are one coalesced float4
    auto contrib = [&](int l, float* c3) {
        float r0 = ra[l*3+0], r1 = ra[l*3+1], r2 = ra[l*3+2];
        float ca, sa, sg, g;
        if (tab4) {
            float4 tv = tab4[l * HH + h];      // coalesced 16B per lane
            ca = tv.x; sa = tv.y; sg = tv.z; g = tv.w;
        } else {
            float a = ang[h*LL + l]; ca = cosf(a); sa = sinf(a);
            g = nw[(size_t)(SS*h + l) * HH + h];
            sg = scaling[SS*h + l] * g;
        }
        float qx = sa*r0, qy = sa*r1, qz = sa*r2;
        float tt = ca*ca - (qx*qx + qy*qy + qz*qz);
        float rv = qx*p1x + qy*p1y + qz*p1z;
        float axv = qy*p1z - qz*p1y;
        float ayv = qz*p1x - qx*p1z;
        float azv = qx*p1y - qy*p1x;
        c3[0] = fmaf(sg, fmaf(tt, p1x, 2.f*fmaf(rv, qx, ca*axv)), g*Px);
        c3[1] = fmaf(sg, fmaf(tt, p1y, 2.f*fmaf(rv, qy, ca*ayv)), g*Py);
        c3[2] = fmaf(sg, fmaf(tt, p1z, 2.f*fmaf(rv, qz, ca*azv)), g*Pz);
    };

    // phase A: low halves (and high half for the last thread) -> LDS write
    if (t < cnt) {
        for (int l = 0; l < SS; ++l) {
            float c3[3]; contrib(l, c3);
            rb[30*t + 3*l + 0] = c3[0];
            rb[30*t + 3*l + 1] = c3[1];
            rb[30*t + 3*l + 2] = c3[2];
        }
        if (t == cnt - 1) {
            for (int l = SS; l < LL; ++l) {
                float c3[3]; contrib(l, c3);
                rb[30*t + 3*l + 0] = c3[0];
                rb[30*t + 3*l + 1] = c3[1];
                rb[30*t + 3*l + 2] = c3[2];
            }
        }
    }
    __syncthreads();
    // phase B: high halves accumulate into neighbor's slots
    if (t < cnt - 1) {
        for (int l = SS; l < LL; ++l) {
            float c3[3]; contrib(l, c3);
            rb[30*t + 3*l + 0] += c3[0];
            rb[30*t + 3*l + 1] += c3[1];
            rb[30*t + 3*l + 2] += c3[2];
        }
    }
    __syncthreads();

    // interior atoms: float4 stores (base is 16B-aligned); boundary: atomicAdd
    float* rdst = recon + ((size_t)b * NN + a0) * 3;
    int interiorEnd = 30 * cnt;
    {
        int ie4 = interiorEnd >> 2;
        float4* r4 = (float4*)rdst;
        for (int q = 8 + t; q < ie4; q += TPB)   // j = 32 .. 4*ie4-1
            r4[q] = make_float4(rb[4*q+0], rb[4*q+1], rb[4*q+2], rb[4*q+3]);
        if (t < 2) rdst[30 + t] = rb[30 + t];    // j = 30, 31
        for (int j = (ie4 << 2) + t; j < interiorEnd; j += TPB) rdst[j] = rb[j];
    }
    if (t < 30) atomicAdd(rdst + t, rb[t]);
    if (t >= 64 && t < 94) {
        int j = interiorEnd + (t - 64);
        atomicAdd(rdst + j, rb[j]);
    }
}

extern "C" void kernel_launch(void* const* d_in, const int* in_sizes, int n_in,
                              void* d_out, int out_size, void* d_ws, size_t ws_size,
                              hipStream_t stream) {
    const float* x       = (const float*)d_in[0];
    const float* W_enc   = (const float*)d_in[1];
    const float* W_dec   = (const float*)d_in[2];
    const float* ang     = (const float*)d_in[3];
    const float* scaling = (const float*)d_in[4];
    float* out = (float*)d_out;

    float4* tab4 = nullptr; float4* wd4 = nullptr;
    size_t need = (size_t)HL * sizeof(float4) * 2;   // 640 KB
    if (ws_size >= need) {
        tab4 = (float4*)d_ws;
        wd4  = tab4 + HL;
    }

    // zero recon (atomic/accumulate base) and the nw/ct region (sparse band)
    hipMemsetAsync(out + O_REC, 0, (size_t)SZ_REC * sizeof(float), stream);
    hipMemsetAsync(out + O_NW, 0, (size_t)(2 * SZ_NH) * sizeof(float), stream);

    if (tab4) k_tab<<<(HL + 255)/256, 256, 0, stream>>>(ang, W_enc, W_dec, scaling, tab4, wd4);
    k_band<<<(NN + 255)/256, 256, 0, stream>>>(W_enc, out + O_NW, out + O_CT);

    k_main<<<BB * NT, TPB, 0, stream>>>(
        x, W_enc, W_dec, ang, tab4, wd4, scaling, out + O_NW,
        out + O_REC, out + O_P, out + O_P1, out + O_P2, out + O_ST, out + O_ROT);
}